// Round 3
// baseline (1445.269 us; speedup 1.0000x reference)
//
#include <hip/hip_runtime.h>
#include <stdint.h>

#define BATCH 4
#define NPTS 8192
#define KNN_K 16
#define CAP 62          // survivor list entries per lane (u16)
#define NSLICE 1024     // candidates per wave (8 waves per query group)

typedef unsigned long long u64;
typedef unsigned short u16;

__device__ __forceinline__ float rl(float v, int s) {
  return __int_as_float(__builtin_amdgcn_readlane(__float_as_int(v), s));
}

// ---------------------------------------------------------------- K0: prep
// cand[i] = (-2x, -2y, -2z, sq)  with sq = fmaf(z,z,fmaf(y,y,x*x))
__global__ __launch_bounds__(256) void k_prep(const float4* __restrict__ xytp,
                                              float4* __restrict__ cand) {
  int i = blockIdx.x * 256 + threadIdx.x;
  float4 p = xytp[i];
  float sq = fmaf(p.z, p.z, fmaf(p.y, p.y, p.x * p.x));
  cand[i] = make_float4(-2.f * p.x, -2.f * p.y, -2.f * p.z, sq);
}

// ---------------------------------------------------------------- K1: knn
// Block = 512 threads (8 waves), one 64-query group per block, query-per-lane.
// Wave w scans candidates [w*1024, (w+1)*1024).
// Candidate fetch: ONE coalesced float4 load per 64 candidates (lane i holds
// candidate i), broadcast via v_readlane into SGPRs -> v_fmac with one SGPR
// operand. No per-candidate memory ops (R2's s_load/lgkmcnt(0) treadmill).
__global__ __launch_bounds__(512, 4) void k_knn(const float4* __restrict__ cand,
                                                int* __restrict__ oidx) {
  __shared__ __align__(16) char s_mem[65536];
  u16* s_app = (u16*)s_mem;   // [(wave*64+lane)*62 + e]
  u64* kb = (u64*)s_mem;      // keys, transposed: kb[(p*8 + list)*64 + lane]

  const int lane = threadIdx.x & 63;
  const int wave = threadIdx.x >> 6;
  const int qg = blockIdx.x & 127;  // N/64 = 128 query groups
  const int b = blockIdx.x >> 7;
  const int n = (qg << 6) + lane;   // this lane's query
  const float4* __restrict__ cb = cand + (b << 13);

  float4 cq = cb[n];
  const float qx = -0.5f * cq.x, qy = -0.5f * cq.y, qz = -0.5f * cq.z;
  const float qsq = cq.w;
  const int j0 = __builtin_amdgcn_readfirstlane(wave * NSLICE);

  // ---- phase 1: branchless threshold scan (8 chains x 2 deep) ----
  // max of the 16 kept values >= true 16th-smallest (16 distinct < t16 is a
  // contradiction), so thr upper-bounds the slice's exact 16th distance.
  float c0[8], c1[8];
#pragma unroll
  for (int m = 0; m < 8; ++m) { c0[m] = INFINITY; c1[m] = INFINITY; }
  {
    float4 A = cb[j0 + lane];
    for (int t = 0; t < NSLICE; t += 64) {
      float4 An = cb[j0 + ((t + 64) & (NSLICE - 1)) + lane];  // prefetch
#pragma unroll
      for (int s = 0; s < 64; ++s) {
        float ax = rl(A.x, s), ay = rl(A.y, s), az = rl(A.z, s),
              aw = rl(A.w, s);
        float d = fmaf(ax, qx, aw);
        d = fmaf(ay, qy, d);
        d = fmaf(az, qz, d);
        int m = s & 7;
        float lo = fminf(d, c0[m]);
        float hi = fmaxf(d, c0[m]);
        c0[m] = lo;
        c1[m] = fminf(hi, c1[m]);
      }
      A = An;
    }
  }
  float thr = c1[0];
#pragma unroll
  for (int m = 1; m < 8; ++m) thr = fmaxf(thr, c1[m]);
  thr += 1e-3f;  // margin >> fp32 rounding between cheap/exact formulas

  // ---- phase 2: survivor append (same broadcast scan, gated append) ----
  u16* my = s_app + ((wave << 6) + lane) * CAP;
  int cnt = 0;
  {
    float4 A = cb[j0 + lane];
    for (int t = 0; t < NSLICE; t += 64) {
      float4 An = cb[j0 + ((t + 64) & (NSLICE - 1)) + lane];
#pragma unroll
      for (int s = 0; s < 64; ++s) {
        float ax = rl(A.x, s), ay = rl(A.y, s), az = rl(A.z, s),
              aw = rl(A.w, s);
        float d = fmaf(ax, qx, aw);
        d = fmaf(ay, qy, d);
        d = fmaf(az, qz, d);
        if (d < thr) {
          if (cnt < CAP) {
            my[cnt] = (u16)(j0 + t + s);
            cnt++;
          } else {
            cnt = CAP + 1;  // overflow marker
          }
        }
      }
      A = An;
    }
  }
  const bool any_ovf = __any(cnt > CAP);

  // ---- phase 3a: exact top-16 of this slice (u64 keys, sorted ascending) ----
  u64 lst[16];
#pragma unroll
  for (int p = 0; p < 16; ++p) lst[p] = ~0ULL;

  if (!any_ovf) {
    for (int e = 0; e < cnt; ++e) {
      int j = my[e];
      float4 A = cb[j];  // divergent gather (L1/L2 hit)
      float xj = -0.5f * A.x, yj = -0.5f * A.y, zj = -0.5f * A.z;
      float dot = qx * xj;
      dot = fmaf(qy, yj, dot);
      dot = fmaf(qz, zj, dot);
      float d2 = (qsq + A.w) - 2.0f * dot;
      unsigned u = __float_as_uint(d2);
      u ^= (0x80000000u | (unsigned)((int)u >> 31));
      u64 key = ((u64)u << 32) | (unsigned)j;
      if (key < lst[15]) {
        u64 x = key;
#pragma unroll
        for (int p = 0; p < 16; ++p) {
          bool sw = x < lst[p];
          u64 a = lst[p];
          lst[p] = sw ? x : a;
          x = sw ? a : x;
        }
      }
    }
  } else {
    // rare fallback: exact rescan of the whole slice
    for (int j = j0; j < j0 + NSLICE; ++j) {
      float4 A = cb[j];
      float xj = -0.5f * A.x, yj = -0.5f * A.y, zj = -0.5f * A.z;
      float dot = qx * xj;
      dot = fmaf(qy, yj, dot);
      dot = fmaf(qz, zj, dot);
      float d2 = (qsq + A.w) - 2.0f * dot;
      unsigned u = __float_as_uint(d2);
      u ^= (0x80000000u | (unsigned)((int)u >> 31));
      u64 key = ((u64)u << 32) | (unsigned)j;
      if (key < lst[15]) {
        u64 x = key;
#pragma unroll
        for (int p = 0; p < 16; ++p) {
          bool sw = x < lst[p];
          u64 a = lst[p];
          lst[p] = sw ? x : a;
          x = sw ? a : x;
        }
      }
    }
  }

  // ---- phase 3b: write slice keys (transposed layout, conflict-free) ----
  __syncthreads();  // all append reads done before reusing s_mem as keys
#pragma unroll
  for (int p = 0; p < 16; ++p) kb[((p << 3) + wave) * 64 + lane] = lst[p];
  __syncthreads();

  // ---- phase 3c: 3-stage pairwise merge (8 -> 4 -> 2 -> 1 lists) ----
  u64 r[16];
  {  // stage A: waves 0..3 merge lists (2w, 2w+1) -> list w
    bool act = wave < 4;
    if (act) {
      int la = 2 * wave, lb = 2 * wave + 1;
      int pa = 0, pb = 0;
      u64 ka = kb[(0 + la) * 64 + lane];
      u64 kv = kb[(0 + lb) * 64 + lane];
#pragma unroll
      for (int k = 0; k < 16; ++k) {
        bool ta = ka < kv;
        r[k] = ta ? ka : kv;
        if (ta) {
          ++pa;
          ka = (pa < 16) ? kb[((pa << 3) + la) * 64 + lane] : ~0ULL;
        } else {
          ++pb;
          kv = (pb < 16) ? kb[((pb << 3) + lb) * 64 + lane] : ~0ULL;
        }
      }
    }
    __syncthreads();
    if (act) {
#pragma unroll
      for (int p = 0; p < 16; ++p) kb[((p << 3) + wave) * 64 + lane] = r[p];
    }
    __syncthreads();
  }
  {  // stage B: waves 0..1 merge lists (2w, 2w+1) -> list w
    bool act = wave < 2;
    if (act) {
      int la = 2 * wave, lb = 2 * wave + 1;
      int pa = 0, pb = 0;
      u64 ka = kb[(0 + la) * 64 + lane];
      u64 kv = kb[(0 + lb) * 64 + lane];
#pragma unroll
      for (int k = 0; k < 16; ++k) {
        bool ta = ka < kv;
        r[k] = ta ? ka : kv;
        if (ta) {
          ++pa;
          ka = (pa < 16) ? kb[((pa << 3) + la) * 64 + lane] : ~0ULL;
        } else {
          ++pb;
          kv = (pb < 16) ? kb[((pb << 3) + lb) * 64 + lane] : ~0ULL;
        }
      }
    }
    __syncthreads();
    if (act) {
#pragma unroll
      for (int p = 0; p < 16; ++p) kb[((p << 3) + wave) * 64 + lane] = r[p];
    }
    __syncthreads();
  }
  if (wave == 0) {  // stage C: final merge -> global
    int pa = 0, pb = 0;
    u64 ka = kb[(0 + 0) * 64 + lane];
    u64 kv = kb[(0 + 1) * 64 + lane];
    const int obase = (((b << 13) + n) << 4);
#pragma unroll
    for (int k = 0; k < 16; ++k) {
      bool ta = ka < kv;
      u64 sel = ta ? ka : kv;
      oidx[obase + k] = (int)(unsigned)(sel & 0xFFFFFFFFull);
      if (ta) {
        ++pa;
        ka = (pa < 16) ? kb[((pa << 3) + 0) * 64 + lane] : ~0ULL;
      } else {
        ++pb;
        kv = (pb < 16) ? kb[((pb << 3) + 1) * 64 + lane] : ~0ULL;
      }
    }
  }
}

// ---------------------------------------------------------------- K2: lt = feat @ lt_w + lt_b
__global__ __launch_bounds__(256) void k_lt(const float* __restrict__ feat,
                                            const float* __restrict__ ltw,
                                            const float* __restrict__ ltb,
                                            float* __restrict__ lt) {
  __shared__ float sw[64][196];
  __shared__ float sf[32][68];
  const int tid = threadIdx.x;
  const int r0 = blockIdx.x * 32;
#pragma unroll
  for (int i = 0; i < 12; ++i) {
    int v = tid + i * 256;
    float4 w4 = ((const float4*)ltw)[v];
    int row = (v * 4) / 192, col = (v * 4) % 192;
    *(float4*)&sw[row][col] = w4;
  }
#pragma unroll
  for (int i = 0; i < 2; ++i) {
    int v = tid + i * 256;
    int row = v >> 4, c4 = v & 15;
    float4 f4 = ((const float4*)(feat + (size_t)(r0 + row) * 64))[c4];
    *(float4*)&sf[row][c4 * 4] = f4;
  }
  __syncthreads();
  const int r = tid >> 3;
  const int c0 = (tid & 7) * 24;
  float acc[24];
#pragma unroll
  for (int l = 0; l < 24; ++l) acc[l] = ltb[c0 + l];
#pragma unroll 4
  for (int j = 0; j < 64; ++j) {
    float f = sf[r][j];
#pragma unroll
    for (int l4 = 0; l4 < 6; ++l4) {
      float4 w4 = *(const float4*)&sw[j][c0 + l4 * 4];
      acc[l4 * 4 + 0] = fmaf(f, w4.x, acc[l4 * 4 + 0]);
      acc[l4 * 4 + 1] = fmaf(f, w4.y, acc[l4 * 4 + 1]);
      acc[l4 * 4 + 2] = fmaf(f, w4.z, acc[l4 * 4 + 2]);
      acc[l4 * 4 + 3] = fmaf(f, w4.w, acc[l4 * 4 + 3]);
    }
  }
  float* orow = lt + (size_t)(r0 + r) * 192 + c0;
#pragma unroll
  for (int l4 = 0; l4 < 6; ++l4)
    *(float4*)&orow[l4 * 4] = make_float4(acc[l4 * 4], acc[l4 * 4 + 1],
                                          acc[l4 * 4 + 2], acc[l4 * 4 + 3]);
}

// ---------------------------------------------------------------- K3: main
__global__ __launch_bounds__(256) void k_main(
    const float4* __restrict__ xytp, const float* __restrict__ lt,
    const int* __restrict__ knn, const float* __restrict__ pe_w1,
    const float* __restrict__ pe_b1, const float* __restrict__ pe_w2,
    const float* __restrict__ pe_b2, const float* __restrict__ ln_g,
    const float* __restrict__ ln_b, float* __restrict__ out) {
  __shared__ float s_h[4][16][64];
  const int lane = threadIdx.x & 63;
  const int wave = threadIdx.x >> 6;
  const int pid = __builtin_amdgcn_readfirstlane(blockIdx.x * 4 + wave);
  const int b = pid >> 13;
  const int n = pid & 8191;

  float w1c[4];
#pragma unroll
  for (int d = 0; d < 4; ++d) w1c[d] = pe_w1[d * 64 + lane];
  const float b1c = pe_b1[lane];
  float w2c[64];
#pragma unroll
  for (int j = 0; j < 64; ++j) w2c[j] = pe_w2[j * 64 + lane];
  const float b2c = pe_b2[lane];
  const float gc = ln_g[lane], bc = ln_b[lane];

  int nb[16];
#pragma unroll
  for (int k = 0; k < 16; ++k) nb[k] = knn[pid * 16 + k];

  const float* __restrict__ ltb = lt + (size_t)(b << 13) * 192;
  float psi[16], alp[16];
#pragma unroll
  for (int k = 0; k < 16; ++k) {
    const float* row = ltb + (size_t)nb[k] * 192;
    psi[k] = row[64 + lane];
    alp[k] = row[128 + lane];
  }
  const float vc = ltb[(size_t)n * 192 + lane];

  const float4 q = xytp[(b << 13) + n];
#pragma unroll
  for (int k = 0; k < 16; ++k) {
    float4 g = xytp[(b << 13) + nb[k]];
    float r0 = q.x - g.x, r1 = q.y - g.y, r2 = q.z - g.z, r3 = q.w - g.w;
    float h = fmaf(r3, w1c[3],
                   fmaf(r2, w1c[2], fmaf(r1, w1c[1], fmaf(r0, w1c[0], b1c))));
    s_h[wave][k][lane] = fmaxf(h, 0.0f);
  }
  __syncthreads();

  float pre[16], apd[16];
#pragma unroll
  for (int k = 0; k < 16; ++k) {
    float acc = b2c;
#pragma unroll
    for (int j4 = 0; j4 < 16; ++j4) {
      float4 h4 = *(const float4*)&s_h[wave][k][j4 * 4];
      acc = fmaf(h4.x, w2c[j4 * 4 + 0], acc);
      acc = fmaf(h4.y, w2c[j4 * 4 + 1], acc);
      acc = fmaf(h4.z, w2c[j4 * 4 + 2], acc);
      acc = fmaf(h4.w, w2c[j4 * 4 + 3], acc);
    }
    pre[k] = (vc - psi[k]) + acc;
    apd[k] = alp[k] + acc;
  }

  float xk[16], m = -INFINITY;
#pragma unroll
  for (int k = 0; k < 16; ++k) {
    float s = pre[k], ss = pre[k] * pre[k];
#pragma unroll
    for (int d = 1; d < 64; d <<= 1) {
      s += __shfl_xor(s, d);
      ss += __shfl_xor(ss, d);
    }
    float mu = s * 0.015625f;
    float var = fmaf(ss, 0.015625f, -mu * mu);
    float inv = 1.0f / sqrtf(var + 1e-5f);
    float lnv = fmaf((pre[k] - mu) * inv, gc, bc);
    xk[k] = lnv * 0.125f;
    m = fmaxf(m, xk[k]);
  }
  float se = 0.f, acc = 0.f;
#pragma unroll
  for (int k = 0; k < 16; ++k) {
    float e = __expf(xk[k] - m);
    se += e;
    acc = fmaf(e, apd[k], acc);
  }
  out[(size_t)pid * 64 + lane] = acc / se;
}

// ---------------------------------------------------------------- launch
extern "C" void kernel_launch(void* const* d_in, const int* in_sizes, int n_in,
                              void* d_out, int out_size, void* d_ws,
                              size_t ws_size, hipStream_t stream) {
  const float4* xytp = (const float4*)d_in[0];
  const float* features = (const float*)d_in[1];
  const float* pe_w1 = (const float*)d_in[2];
  const float* pe_b1 = (const float*)d_in[3];
  const float* pe_w2 = (const float*)d_in[4];
  const float* pe_b2 = (const float*)d_in[5];
  const float* lt_w = (const float*)d_in[6];
  const float* lt_b = (const float*)d_in[7];
  const float* ln_g = (const float*)d_in[8];
  const float* ln_b = (const float*)d_in[9];
  float* out = (float*)d_out;

  char* ws = (char*)d_ws;
  float4* cand = (float4*)ws;                   // 524288 B
  int* idxbuf = (int*)(ws + 524288);            // 2097152 B
  float* lt = (float*)(ws + 524288 + 2097152);  // 25165824 B

  k_prep<<<(BATCH * NPTS) / 256, 256, 0, stream>>>(xytp, cand);
  k_knn<<<BATCH * (NPTS / 64), 512, 0, stream>>>(cand, idxbuf);
  k_lt<<<(BATCH * NPTS) / 32, 256, 0, stream>>>(features, lt_w, lt_b, lt);
  k_main<<<(BATCH * NPTS) / 4, 256, 0, stream>>>(xytp, lt, idxbuf, pe_w1,
                                                 pe_b1, pe_w2, pe_b2, ln_g,
                                                 ln_b, out);
}

// Round 4
// 1319.163 us; speedup vs baseline: 1.0956x; 1.0956x over previous
//
#include <hip/hip_runtime.h>
#include <stdint.h>

#define BATCH 4
#define NPTS 8192
#define KNN_K 16
#define CAP 48          // survivor list entries per lane (u16)
#define NSLICE 1024     // candidates per wave (8 waves per query group)
#define CHUNK 128       // candidates staged per LDS buffer

typedef unsigned long long u64;
typedef unsigned short u16;

// ---------------------------------------------------------------- K0: prep
// cand[i] = (-2x, -2y, -2z, sq)  with sq = fmaf(z,z,fmaf(y,y,x*x))
__global__ __launch_bounds__(256) void k_prep(const float4* __restrict__ xytp,
                                              float4* __restrict__ cand) {
  int i = blockIdx.x * 256 + threadIdx.x;
  float4 p = xytp[i];
  float sq = fmaf(p.z, p.z, fmaf(p.y, p.y, p.x * p.x));
  cand[i] = make_float4(-2.f * p.x, -2.f * p.y, -2.f * p.z, sq);
}

// ---------------------------------------------------------------- K1: knn
// Block = 512 threads (8 waves), one 64-query group per block, query-per-lane.
// Wave w scans candidates [w*1024, (w+1)*1024) in 128-candidate LDS chunks
// (per-wave double buffer).  Candidate fetch inside the hot loop is a
// uniform-address ds_read_b128 broadcast (LDS pipe) — zero readlane / s_load
// ops in the body (R2/R3's treadmill).  Phase 1: depth-3 x 8-chain cascade
// gives thr >= exact 16th (24 kept values).  Phase 2: rescan, append
// survivors.  Phase 3: exact re-rank + 8->1 merge (unchanged from R3).
__global__ __launch_bounds__(512, 4) void k_knn(const float4* __restrict__ cand,
                                                int* __restrict__ oidx) {
  __shared__ __align__(16) char s_mem[81920];   // 80 KB -> 2 blocks/CU
  float4* s_ch = (float4*)s_mem;                // [8 waves][2 bufs][128] = 32 KB
  u16* s_app = (u16*)(s_mem + 32768);           // [512][CAP] = 48 KB
  u64* kb = (u64*)s_mem;                        // merge keys (post-sync reuse)

  const int lane = threadIdx.x & 63;
  const int wave = threadIdx.x >> 6;
  const int qg = blockIdx.x & 127;  // N/64 = 128 query groups
  const int b = blockIdx.x >> 7;
  const int n = (qg << 6) + lane;   // this lane's query
  const float4* __restrict__ cb = cand + (b << 13);

  float4 cq = cb[n];
  const float qx = -0.5f * cq.x, qy = -0.5f * cq.y, qz = -0.5f * cq.z;
  const float qsq = cq.w;
  const int j0 = __builtin_amdgcn_readfirstlane(wave * NSLICE);

  float4* buf0 = s_ch + (wave * 2 + 0) * CHUNK;
  float4* buf1 = s_ch + (wave * 2 + 1) * CHUNK;

  // ---- phase 1: branchless threshold scan (8 chains x depth 3) ----
  // 24 kept values; max of chain 3rd-minima >= true 16th-smallest of slice.
  float c0[8], c1[8], c2[8];
#pragma unroll
  for (int m = 0; m < 8; ++m) { c0[m] = INFINITY; c1[m] = INFINITY; c2[m] = INFINITY; }
  {
    float4 r0 = cb[j0 + lane];
    float4 r1 = cb[j0 + 64 + lane];
    for (int t = 0; t < NSLICE; t += CHUNK) {
      float4* bw = (t & CHUNK) ? buf1 : buf0;
      bw[lane] = r0;
      bw[64 + lane] = r1;
      int tn = t + CHUNK;
      if (tn < NSLICE) {  // prefetch next chunk (hidden behind this chunk)
        r0 = cb[j0 + tn + lane];
        r1 = cb[j0 + tn + 64 + lane];
      }
#pragma unroll 8
      for (int c = 0; c < CHUNK; ++c) {
        float4 A = bw[c];  // uniform addr -> ds_read_b128 broadcast
        float d = fmaf(A.x, qx, A.w);
        d = fmaf(A.y, qy, d);
        d = fmaf(A.z, qz, d);
        int m = c & 7;
        float lo = fminf(d, c0[m]);
        float hi = fmaxf(d, c0[m]);
        c0[m] = lo;
        float lo2 = fminf(hi, c1[m]);
        float hi2 = fmaxf(hi, c1[m]);
        c1[m] = lo2;
        c2[m] = fminf(hi2, c2[m]);
      }
    }
  }
  float thr = c2[0];
#pragma unroll
  for (int m = 1; m < 8; ++m) thr = fmaxf(thr, c2[m]);
  thr += 1e-3f;  // margin >> fp32 rounding between cheap/exact formulas

  // ---- phase 2: survivor append (same LDS-broadcast scan, gated append) ----
  u16* my = s_app + ((wave << 6) + lane) * CAP;
  int cnt = 0;
  {
    float4 r0 = cb[j0 + lane];
    float4 r1 = cb[j0 + 64 + lane];
    for (int t = 0; t < NSLICE; t += CHUNK) {
      float4* bw = (t & CHUNK) ? buf1 : buf0;
      bw[lane] = r0;
      bw[64 + lane] = r1;
      int tn = t + CHUNK;
      if (tn < NSLICE) {
        r0 = cb[j0 + tn + lane];
        r1 = cb[j0 + tn + 64 + lane];
      }
#pragma unroll 8
      for (int c = 0; c < CHUNK; ++c) {
        float4 A = bw[c];
        float d = fmaf(A.x, qx, A.w);
        d = fmaf(A.y, qy, d);
        d = fmaf(A.z, qz, d);
        if (d < thr) {
          if (cnt < CAP) {
            my[cnt] = (u16)(j0 + t + c);
            cnt++;
          } else {
            cnt = CAP + 1;  // overflow marker
          }
        }
      }
    }
  }
  const bool any_ovf = __any(cnt > CAP);

  // ---- phase 3a: exact top-16 of this slice (u64 keys, sorted ascending) ----
  u64 lst[16];
#pragma unroll
  for (int p = 0; p < 16; ++p) lst[p] = ~0ULL;

  if (!any_ovf) {
    for (int e = 0; e < cnt; ++e) {
      int j = my[e];
      float4 A = cb[j];  // divergent gather (L1/L2 hit)
      float xj = -0.5f * A.x, yj = -0.5f * A.y, zj = -0.5f * A.z;
      float dot = qx * xj;
      dot = fmaf(qy, yj, dot);
      dot = fmaf(qz, zj, dot);
      float d2 = (qsq + A.w) - 2.0f * dot;
      unsigned u = __float_as_uint(d2);
      u ^= (0x80000000u | (unsigned)((int)u >> 31));
      u64 key = ((u64)u << 32) | (unsigned)j;
      if (key < lst[15]) {
        u64 x = key;
#pragma unroll
        for (int p = 0; p < 16; ++p) {
          bool sw = x < lst[p];
          u64 a = lst[p];
          lst[p] = sw ? x : a;
          x = sw ? a : x;
        }
      }
    }
  } else {
    // rare fallback: exact rescan of the whole slice from global
    for (int j = j0; j < j0 + NSLICE; ++j) {
      float4 A = cb[j];
      float xj = -0.5f * A.x, yj = -0.5f * A.y, zj = -0.5f * A.z;
      float dot = qx * xj;
      dot = fmaf(qy, yj, dot);
      dot = fmaf(qz, zj, dot);
      float d2 = (qsq + A.w) - 2.0f * dot;
      unsigned u = __float_as_uint(d2);
      u ^= (0x80000000u | (unsigned)((int)u >> 31));
      u64 key = ((u64)u << 32) | (unsigned)j;
      if (key < lst[15]) {
        u64 x = key;
#pragma unroll
        for (int p = 0; p < 16; ++p) {
          bool sw = x < lst[p];
          u64 a = lst[p];
          lst[p] = sw ? x : a;
          x = sw ? a : x;
        }
      }
    }
  }

  // ---- phase 3b: write slice keys (transposed layout, conflict-free) ----
  __syncthreads();  // all append/chunk reads done before reusing s_mem as keys
#pragma unroll
  for (int p = 0; p < 16; ++p) kb[((p << 3) + wave) * 64 + lane] = lst[p];
  __syncthreads();

  // ---- phase 3c: 3-stage pairwise merge (8 -> 4 -> 2 -> 1 lists) ----
  u64 r[16];
  {  // stage A: waves 0..3 merge lists (2w, 2w+1) -> list w
    bool act = wave < 4;
    if (act) {
      int la = 2 * wave, lb = 2 * wave + 1;
      int pa = 0, pb = 0;
      u64 ka = kb[(0 + la) * 64 + lane];
      u64 kv = kb[(0 + lb) * 64 + lane];
#pragma unroll
      for (int k = 0; k < 16; ++k) {
        bool ta = ka < kv;
        r[k] = ta ? ka : kv;
        if (ta) {
          ++pa;
          ka = (pa < 16) ? kb[((pa << 3) + la) * 64 + lane] : ~0ULL;
        } else {
          ++pb;
          kv = (pb < 16) ? kb[((pb << 3) + lb) * 64 + lane] : ~0ULL;
        }
      }
    }
    __syncthreads();
    if (act) {
#pragma unroll
      for (int p = 0; p < 16; ++p) kb[((p << 3) + wave) * 64 + lane] = r[p];
    }
    __syncthreads();
  }
  {  // stage B: waves 0..1 merge lists (2w, 2w+1) -> list w
    bool act = wave < 2;
    if (act) {
      int la = 2 * wave, lb = 2 * wave + 1;
      int pa = 0, pb = 0;
      u64 ka = kb[(0 + la) * 64 + lane];
      u64 kv = kb[(0 + lb) * 64 + lane];
#pragma unroll
      for (int k = 0; k < 16; ++k) {
        bool ta = ka < kv;
        r[k] = ta ? ka : kv;
        if (ta) {
          ++pa;
          ka = (pa < 16) ? kb[((pa << 3) + la) * 64 + lane] : ~0ULL;
        } else {
          ++pb;
          kv = (pb < 16) ? kb[((pb << 3) + lb) * 64 + lane] : ~0ULL;
        }
      }
    }
    __syncthreads();
    if (act) {
#pragma unroll
      for (int p = 0; p < 16; ++p) kb[((p << 3) + wave) * 64 + lane] = r[p];
    }
    __syncthreads();
  }
  if (wave == 0) {  // stage C: final merge -> global
    int pa = 0, pb = 0;
    u64 ka = kb[(0 + 0) * 64 + lane];
    u64 kv = kb[(0 + 1) * 64 + lane];
    const int obase = (((b << 13) + n) << 4);
#pragma unroll
    for (int k = 0; k < 16; ++k) {
      bool ta = ka < kv;
      u64 sel = ta ? ka : kv;
      oidx[obase + k] = (int)(unsigned)(sel & 0xFFFFFFFFull);
      if (ta) {
        ++pa;
        ka = (pa < 16) ? kb[((pa << 3) + 0) * 64 + lane] : ~0ULL;
      } else {
        ++pb;
        kv = (pb < 16) ? kb[((pb << 3) + 1) * 64 + lane] : ~0ULL;
      }
    }
  }
}

// ---------------------------------------------------------------- K2: lt = feat @ lt_w + lt_b
__global__ __launch_bounds__(256) void k_lt(const float* __restrict__ feat,
                                            const float* __restrict__ ltw,
                                            const float* __restrict__ ltb,
                                            float* __restrict__ lt) {
  __shared__ float sw[64][196];
  __shared__ float sf[32][68];
  const int tid = threadIdx.x;
  const int r0 = blockIdx.x * 32;
#pragma unroll
  for (int i = 0; i < 12; ++i) {
    int v = tid + i * 256;
    float4 w4 = ((const float4*)ltw)[v];
    int row = (v * 4) / 192, col = (v * 4) % 192;
    *(float4*)&sw[row][col] = w4;
  }
#pragma unroll
  for (int i = 0; i < 2; ++i) {
    int v = tid + i * 256;
    int row = v >> 4, c4 = v & 15;
    float4 f4 = ((const float4*)(feat + (size_t)(r0 + row) * 64))[c4];
    *(float4*)&sf[row][c4 * 4] = f4;
  }
  __syncthreads();
  const int r = tid >> 3;
  const int c0 = (tid & 7) * 24;
  float acc[24];
#pragma unroll
  for (int l = 0; l < 24; ++l) acc[l] = ltb[c0 + l];
#pragma unroll 4
  for (int j = 0; j < 64; ++j) {
    float f = sf[r][j];
#pragma unroll
    for (int l4 = 0; l4 < 6; ++l4) {
      float4 w4 = *(const float4*)&sw[j][c0 + l4 * 4];
      acc[l4 * 4 + 0] = fmaf(f, w4.x, acc[l4 * 4 + 0]);
      acc[l4 * 4 + 1] = fmaf(f, w4.y, acc[l4 * 4 + 1]);
      acc[l4 * 4 + 2] = fmaf(f, w4.z, acc[l4 * 4 + 2]);
      acc[l4 * 4 + 3] = fmaf(f, w4.w, acc[l4 * 4 + 3]);
    }
  }
  float* orow = lt + (size_t)(r0 + r) * 192 + c0;
#pragma unroll
  for (int l4 = 0; l4 < 6; ++l4)
    *(float4*)&orow[l4 * 4] = make_float4(acc[l4 * 4], acc[l4 * 4 + 1],
                                          acc[l4 * 4 + 2], acc[l4 * 4 + 3]);
}

// ---------------------------------------------------------------- K3: main
__global__ __launch_bounds__(256) void k_main(
    const float4* __restrict__ xytp, const float* __restrict__ lt,
    const int* __restrict__ knn, const float* __restrict__ pe_w1,
    const float* __restrict__ pe_b1, const float* __restrict__ pe_w2,
    const float* __restrict__ pe_b2, const float* __restrict__ ln_g,
    const float* __restrict__ ln_b, float* __restrict__ out) {
  __shared__ float s_h[4][16][64];
  const int lane = threadIdx.x & 63;
  const int wave = threadIdx.x >> 6;
  const int pid = __builtin_amdgcn_readfirstlane(blockIdx.x * 4 + wave);
  const int b = pid >> 13;
  const int n = pid & 8191;

  float w1c[4];
#pragma unroll
  for (int d = 0; d < 4; ++d) w1c[d] = pe_w1[d * 64 + lane];
  const float b1c = pe_b1[lane];
  float w2c[64];
#pragma unroll
  for (int j = 0; j < 64; ++j) w2c[j] = pe_w2[j * 64 + lane];
  const float b2c = pe_b2[lane];
  const float gc = ln_g[lane], bc = ln_b[lane];

  int nb[16];
#pragma unroll
  for (int k = 0; k < 16; ++k) nb[k] = knn[pid * 16 + k];

  const float* __restrict__ ltb = lt + (size_t)(b << 13) * 192;
  float psi[16], alp[16];
#pragma unroll
  for (int k = 0; k < 16; ++k) {
    const float* row = ltb + (size_t)nb[k] * 192;
    psi[k] = row[64 + lane];
    alp[k] = row[128 + lane];
  }
  const float vc = ltb[(size_t)n * 192 + lane];

  const float4 q = xytp[(b << 13) + n];
#pragma unroll
  for (int k = 0; k < 16; ++k) {
    float4 g = xytp[(b << 13) + nb[k]];
    float r0 = q.x - g.x, r1 = q.y - g.y, r2 = q.z - g.z, r3 = q.w - g.w;
    float h = fmaf(r3, w1c[3],
                   fmaf(r2, w1c[2], fmaf(r1, w1c[1], fmaf(r0, w1c[0], b1c))));
    s_h[wave][k][lane] = fmaxf(h, 0.0f);
  }
  __syncthreads();

  float pre[16], apd[16];
#pragma unroll
  for (int k = 0; k < 16; ++k) {
    float acc = b2c;
#pragma unroll
    for (int j4 = 0; j4 < 16; ++j4) {
      float4 h4 = *(const float4*)&s_h[wave][k][j4 * 4];
      acc = fmaf(h4.x, w2c[j4 * 4 + 0], acc);
      acc = fmaf(h4.y, w2c[j4 * 4 + 1], acc);
      acc = fmaf(h4.z, w2c[j4 * 4 + 2], acc);
      acc = fmaf(h4.w, w2c[j4 * 4 + 3], acc);
    }
    pre[k] = (vc - psi[k]) + acc;
    apd[k] = alp[k] + acc;
  }

  float xk[16], m = -INFINITY;
#pragma unroll
  for (int k = 0; k < 16; ++k) {
    float s = pre[k], ss = pre[k] * pre[k];
#pragma unroll
    for (int d = 1; d < 64; d <<= 1) {
      s += __shfl_xor(s, d);
      ss += __shfl_xor(ss, d);
    }
    float mu = s * 0.015625f;
    float var = fmaf(ss, 0.015625f, -mu * mu);
    float inv = 1.0f / sqrtf(var + 1e-5f);
    float lnv = fmaf((pre[k] - mu) * inv, gc, bc);
    xk[k] = lnv * 0.125f;
    m = fmaxf(m, xk[k]);
  }
  float se = 0.f, acc = 0.f;
#pragma unroll
  for (int k = 0; k < 16; ++k) {
    float e = __expf(xk[k] - m);
    se += e;
    acc = fmaf(e, apd[k], acc);
  }
  out[(size_t)pid * 64 + lane] = acc / se;
}

// ---------------------------------------------------------------- launch
extern "C" void kernel_launch(void* const* d_in, const int* in_sizes, int n_in,
                              void* d_out, int out_size, void* d_ws,
                              size_t ws_size, hipStream_t stream) {
  const float4* xytp = (const float4*)d_in[0];
  const float* features = (const float*)d_in[1];
  const float* pe_w1 = (const float*)d_in[2];
  const float* pe_b1 = (const float*)d_in[3];
  const float* pe_w2 = (const float*)d_in[4];
  const float* pe_b2 = (const float*)d_in[5];
  const float* lt_w = (const float*)d_in[6];
  const float* lt_b = (const float*)d_in[7];
  const float* ln_g = (const float*)d_in[8];
  const float* ln_b = (const float*)d_in[9];
  float* out = (float*)d_out;

  char* ws = (char*)d_ws;
  float4* cand = (float4*)ws;                   // 524288 B
  int* idxbuf = (int*)(ws + 524288);            // 2097152 B
  float* lt = (float*)(ws + 524288 + 2097152);  // 25165824 B

  k_prep<<<(BATCH * NPTS) / 256, 256, 0, stream>>>(xytp, cand);
  k_knn<<<BATCH * (NPTS / 64), 512, 0, stream>>>(cand, idxbuf);
  k_lt<<<(BATCH * NPTS) / 32, 256, 0, stream>>>(features, lt_w, lt_b, lt);
  k_main<<<(BATCH * NPTS) / 4, 256, 0, stream>>>(xytp, lt, idxbuf, pe_w1,
                                                 pe_b1, pe_w2, pe_b2, ln_g,
                                                 ln_b, out);
}

// Round 5
// 975.417 us; speedup vs baseline: 1.4817x; 1.3524x over previous
//
#include <hip/hip_runtime.h>
#include <stdint.h>

#define BATCH 4
#define NPTS 8192
#define KNN_K 16
#define CAP 32          // survivor entries per lane (u16); +1 scratch row
#define NTILE 128       // 16-cand tiles per 2048-cand slice

typedef unsigned long long u64;
typedef unsigned short u16;
typedef _Float16 half8 __attribute__((ext_vector_type(8)));
typedef float f32x4v __attribute__((ext_vector_type(4)));

// ---------------------------------------------------------------- K0: prep
// Per point: fp16 hi/lo-split MFMA slot vectors so ONE mfma_f32_16x16x32_f16
// computes d2 = sq_i + sq_j - 2*x.x' directly (K-slots 0..12 used, 13..15
// zero; quads 2..3 of the wave supply zeros via zbuf).
// y = sqrt(2)*x, split y = yh + yl (fp16);  sq split sh + sl.
// A slots: {yh,yh,yl}x3, sh, sl, 1, 1, 0,0,0
// B slots: {-yh,-yl,-yh}x3, 1, 1, sh, sl, 0,0,0
// => sum_k a_k*b_k = sq_i + sq_j - (yh yh' + yh yl' + yl yh')*3c  ~= d2,
//    |err| <= ~1e-3 (missing yl*yl' + fp16 split residue).
__global__ __launch_bounds__(256) void k_prep(const float4* __restrict__ xytp,
                                              _Float16* __restrict__ aslot,
                                              _Float16* __restrict__ bslot,
                                              _Float16* __restrict__ zbuf) {
  int i = blockIdx.x * 256 + threadIdx.x;
  float4 v = xytp[i];
  float sq = fmaf(v.z, v.z, fmaf(v.y, v.y, v.x * v.x));
  const float R2 = 1.41421356237309515f;
  float yx = R2 * v.x, yy = R2 * v.y, yz = R2 * v.z;
  _Float16 hx = (_Float16)yx, hy = (_Float16)yy, hz = (_Float16)yz;
  _Float16 lx = (_Float16)(yx - (float)hx);
  _Float16 ly = (_Float16)(yy - (float)hy);
  _Float16 lz = (_Float16)(yz - (float)hz);
  _Float16 sh = (_Float16)sq, sl = (_Float16)(sq - (float)sh);
  _Float16 one = (_Float16)1.0f, zer = (_Float16)0.0f;

  _Float16* a = aslot + (size_t)i * 16;
  a[0] = hx; a[1] = hx; a[2] = lx;
  a[3] = hy; a[4] = hy; a[5] = ly;
  a[6] = hz; a[7] = hz; a[8] = lz;
  a[9] = sh; a[10] = sl; a[11] = one; a[12] = one;
  a[13] = zer; a[14] = zer; a[15] = zer;

  _Float16* bq = bslot + (size_t)i * 16;
  bq[0] = -hx; bq[1] = -lx; bq[2] = -hx;
  bq[3] = -hy; bq[4] = -ly; bq[5] = -hy;
  bq[6] = -hz; bq[7] = -lz; bq[8] = -hz;
  bq[9] = one; bq[10] = one; bq[11] = sh; bq[12] = sl;
  bq[13] = zer; bq[14] = zer; bq[15] = zer;

  if (i < 16) zbuf[i] = zer;
}

// ---------------------------------------------------------------- K1: knn
// Block = 256 thr (4 waves) = one 16-query tile; wave w scans slice
// [w*2048,(w+1)*2048) as 128 MFMA tiles.  Lane (q4,q): query q=lane&15,
// row-group q4=lane>>4 covers rows 4q4..4q4+3 of every tile (C-layout).
// Pass 1: per-lane tile-min -> 4-chain depth-4 cascade -> thr bound on the
// lane's 512-cand subset t16; thr = min over quads (valid: slice-t16 <=
// every subset-t16).  Pass 2: recompute, branchless compaction append.
// Phase 3: exact fp32 re-rank (formula identical to validated R4) + 16-way
// per-query merge tree (4 quads x 4 slices).
__global__ __launch_bounds__(256, 4) void k_knn(
    const float4* __restrict__ xytp, const _Float16* __restrict__ aslot,
    const _Float16* __restrict__ bslot, const _Float16* __restrict__ zbuf,
    u16* __restrict__ oidx) {
  __shared__ __align__(16) char s_mem[32768];
  u16* s_app = (u16*)s_mem;  // [CAP+1][256], interleaved: slot*256+tid
  u64* kb = (u64*)s_mem;     // [16][256] merge keys (post-sync reuse)

  const int tid = threadIdx.x;
  const int lane = tid & 63;
  const int wave = tid >> 6;
  const int q = lane & 15;
  const int q4 = lane >> 4;
  const int qg = blockIdx.x & 511;  // NPTS/16 query tiles
  const int b = blockIdx.x >> 9;
  const int gb = b << 13;
  const int sb = wave << 11;  // slice base

  // exact query values (same formula as validated exact path)
  const int qi = (qg << 4) + q;
  const float4 qv = xytp[gb + qi];
  const float qsq = fmaf(qv.z, qv.z, fmaf(qv.y, qv.y, qv.x * qv.x));

  // B fragment (fixed for the whole kernel): B[n=q][k=q4*8+j]; k>=16 zero.
  half8 bfr = {};
  if (q4 < 2)
    bfr = *(const half8*)(bslot + ((size_t)(gb + qi) << 4) + (q4 << 3));

  // A fragment pointer: A[m=lane&15][k=q4*8+j]; quads 2,3 read zbuf.
  const half8* ap;
  int astep;
  if (q4 < 2) {
    ap = (const half8*)(aslot + ((size_t)(gb + sb + q) << 4) + (q4 << 3));
    astep = 32;  // 16 points * 16 halfs = 32 half8 per tile
  } else {
    ap = (const half8*)zbuf;
    astep = 0;
  }
  f32x4v zc = {0.f, 0.f, 0.f, 0.f};

  // ---- pass 1: per-lane tile-min cascade (4 chains x depth 4 = 16 kept) ----
  float c0[4], c1[4], c2[4], c3[4];
#pragma unroll
  for (int m = 0; m < 4; ++m) {
    c0[m] = INFINITY; c1[m] = INFINITY; c2[m] = INFINITY; c3[m] = INFINITY;
  }
#pragma unroll 4
  for (int t = 0; t < NTILE; ++t) {
    half8 a = ap[t * astep];
    f32x4v d = __builtin_amdgcn_mfma_f32_16x16x32_f16(a, bfr, zc, 0, 0, 0);
    float tm = fminf(fminf(d[0], d[1]), fminf(d[2], d[3]));
    const int m = t & 3;
    float lo = fminf(tm, c0[m]);
    float hi = fmaxf(tm, c0[m]);
    c0[m] = lo;
    float lo2 = fminf(hi, c1[m]);
    float hi2 = fmaxf(hi, c1[m]);
    c1[m] = lo2;
    float lo3 = fminf(hi2, c2[m]);
    float hi3 = fmaxf(hi2, c2[m]);
    c2[m] = lo3;
    c3[m] = fminf(hi3, c3[m]);
  }
  float thr = fmaxf(fmaxf(c3[0], c3[1]), fmaxf(c3[2], c3[3]));
  // tighten across quads: slice-t16 <= subset-t16 for every quad
  thr = fminf(thr, __shfl_xor(thr, 16));
  thr = fminf(thr, __shfl_xor(thr, 32));
  thr += 4e-3f;  // covers fp16-split approx error both directions

  // ---- pass 2: branchless survivor compaction ----
  int cnt = 0;
#pragma unroll 4
  for (int t = 0; t < NTILE; ++t) {
    half8 a = ap[t * astep];
    f32x4v d = __builtin_amdgcn_mfma_f32_16x16x32_f16(a, bfr, zc, 0, 0, 0);
    int idb = sb + (t << 4) + (q4 << 2);
#pragma unroll
    for (int r = 0; r < 4; ++r) {
      bool keep = d[r] < thr;
      int slot = cnt < CAP ? cnt : CAP;  // row CAP = scratch
      s_app[slot * 256 + tid] = (u16)(idb + r);
      cnt += keep;
    }
  }
  const bool ovf = __any(cnt > CAP);

  // ---- phase 3a: exact top-16 (u64 lexicographic keys), per lane ----
  u64 lst[16];
#pragma unroll
  for (int p = 0; p < 16; ++p) lst[p] = ~0ULL;

  if (!ovf) {
    for (int e = 0; e < cnt; ++e) {
      int j = s_app[e * 256 + tid];
      float4 A = xytp[gb + j];
      float sqj = fmaf(A.z, A.z, fmaf(A.y, A.y, A.x * A.x));
      float dot = qv.x * A.x;
      dot = fmaf(qv.y, A.y, dot);
      dot = fmaf(qv.z, A.z, dot);
      float d2 = (qsq + sqj) - 2.0f * dot;
      unsigned u = __float_as_uint(d2);
      u ^= (0x80000000u | (unsigned)((int)u >> 31));
      u64 key = ((u64)u << 32) | (unsigned)j;
      if (key < lst[15]) {
        u64 x = key;
#pragma unroll
        for (int p = 0; p < 16; ++p) {
          bool sw = x < lst[p];
          u64 a = lst[p];
          lst[p] = sw ? x : a;
          x = sw ? a : x;
        }
      }
    }
  } else {
    // rare fallback: exact scan of this lane's own 512-candidate subset
    for (int t = 0; t < NTILE; ++t) {
#pragma unroll
      for (int r = 0; r < 4; ++r) {
        int j = sb + (t << 4) + (q4 << 2) + r;
        float4 A = xytp[gb + j];
        float sqj = fmaf(A.z, A.z, fmaf(A.y, A.y, A.x * A.x));
        float dot = qv.x * A.x;
        dot = fmaf(qv.y, A.y, dot);
        dot = fmaf(qv.z, A.z, dot);
        float d2 = (qsq + sqj) - 2.0f * dot;
        unsigned u = __float_as_uint(d2);
        u ^= (0x80000000u | (unsigned)((int)u >> 31));
        u64 key = ((u64)u << 32) | (unsigned)j;
        if (key < lst[15]) {
          u64 x = key;
#pragma unroll
          for (int p = 0; p < 16; ++p) {
            bool sw = x < lst[p];
            u64 a = lst[p];
            lst[p] = sw ? x : a;
            x = sw ? a : x;
          }
        }
      }
    }
  }

  // ---- phase 3b: write keys; list L = q*16 + wave*4 + q4 ----
  __syncthreads();  // all s_app reads done before reusing s_mem as keys
  const int L = (q << 4) + (wave << 2) + q4;
#pragma unroll
  for (int p = 0; p < 16; ++p) kb[(p << 8) + L] = lst[p];
  __syncthreads();

  // ---- phase 3c: 4-round merge tree (16 lists/query -> 1) ----
#pragma unroll
  for (int r = 0; r < 4; ++r) {
    const int nm = 128 >> r;
    if (tid < nm) {
      const int la = (2 * tid) << r;
      const int lb = (2 * tid + 1) << r;
      u64 rb[16];
      int pa = 0, pb = 0;
      u64 ka = kb[la], kv = kb[lb];
#pragma unroll
      for (int k = 0; k < 16; ++k) {
        bool ta = ka < kv;
        rb[k] = ta ? ka : kv;
        if (ta) {
          ++pa;
          ka = (pa < 16) ? kb[(pa << 8) + la] : ~0ULL;
        } else {
          ++pb;
          kv = (pb < 16) ? kb[(pb << 8) + lb] : ~0ULL;
        }
      }
#pragma unroll
      for (int p = 0; p < 16; ++p) kb[(p << 8) + la] = rb[p];
    }
    __syncthreads();
  }

  // ---- output: final list of query qq at column qq*16 ----
  {
    const int qq = tid >> 4, k = tid & 15;
    u64 key = kb[(k << 8) + (qq << 4)];
    oidx[((size_t)(gb + (qg << 4) + qq) << 4) + k] = (u16)key;  // j < 8192
  }
}

// ---------------------------------------------------------------- K2: lt = feat @ lt_w + lt_b
__global__ __launch_bounds__(256) void k_lt(const float* __restrict__ feat,
                                            const float* __restrict__ ltw,
                                            const float* __restrict__ ltb,
                                            float* __restrict__ lt) {
  __shared__ float sw[64][196];
  __shared__ float sf[32][68];
  const int tid = threadIdx.x;
  const int r0 = blockIdx.x * 32;
#pragma unroll
  for (int i = 0; i < 12; ++i) {
    int v = tid + i * 256;
    float4 w4 = ((const float4*)ltw)[v];
    int row = (v * 4) / 192, col = (v * 4) % 192;
    *(float4*)&sw[row][col] = w4;
  }
#pragma unroll
  for (int i = 0; i < 2; ++i) {
    int v = tid + i * 256;
    int row = v >> 4, c4 = v & 15;
    float4 f4 = ((const float4*)(feat + (size_t)(r0 + row) * 64))[c4];
    *(float4*)&sf[row][c4 * 4] = f4;
  }
  __syncthreads();
  const int r = tid >> 3;
  const int c0 = (tid & 7) * 24;
  float acc[24];
#pragma unroll
  for (int l = 0; l < 24; ++l) acc[l] = ltb[c0 + l];
#pragma unroll 4
  for (int j = 0; j < 64; ++j) {
    float f = sf[r][j];
#pragma unroll
    for (int l4 = 0; l4 < 6; ++l4) {
      float4 w4 = *(const float4*)&sw[j][c0 + l4 * 4];
      acc[l4 * 4 + 0] = fmaf(f, w4.x, acc[l4 * 4 + 0]);
      acc[l4 * 4 + 1] = fmaf(f, w4.y, acc[l4 * 4 + 1]);
      acc[l4 * 4 + 2] = fmaf(f, w4.z, acc[l4 * 4 + 2]);
      acc[l4 * 4 + 3] = fmaf(f, w4.w, acc[l4 * 4 + 3]);
    }
  }
  float* orow = lt + (size_t)(r0 + r) * 192 + c0;
#pragma unroll
  for (int l4 = 0; l4 < 6; ++l4)
    *(float4*)&orow[l4 * 4] = make_float4(acc[l4 * 4], acc[l4 * 4 + 1],
                                          acc[l4 * 4 + 2], acc[l4 * 4 + 3]);
}

// ---------------------------------------------------------------- K3: main
__global__ __launch_bounds__(256) void k_main(
    const float4* __restrict__ xytp, const float* __restrict__ lt,
    const u16* __restrict__ knn, const float* __restrict__ pe_w1,
    const float* __restrict__ pe_b1, const float* __restrict__ pe_w2,
    const float* __restrict__ pe_b2, const float* __restrict__ ln_g,
    const float* __restrict__ ln_b, float* __restrict__ out) {
  __shared__ float s_h[4][16][64];
  const int lane = threadIdx.x & 63;
  const int wave = threadIdx.x >> 6;
  const int pid = __builtin_amdgcn_readfirstlane(blockIdx.x * 4 + wave);
  const int b = pid >> 13;
  const int n = pid & 8191;

  float w1c[4];
#pragma unroll
  for (int d = 0; d < 4; ++d) w1c[d] = pe_w1[d * 64 + lane];
  const float b1c = pe_b1[lane];
  float w2c[64];
#pragma unroll
  for (int j = 0; j < 64; ++j) w2c[j] = pe_w2[j * 64 + lane];
  const float b2c = pe_b2[lane];
  const float gc = ln_g[lane], bc = ln_b[lane];

  int nb[16];
#pragma unroll
  for (int k = 0; k < 16; ++k) nb[k] = knn[pid * 16 + k];

  const float* __restrict__ ltb = lt + (size_t)(b << 13) * 192;
  float psi[16], alp[16];
#pragma unroll
  for (int k = 0; k < 16; ++k) {
    const float* row = ltb + (size_t)nb[k] * 192;
    psi[k] = row[64 + lane];
    alp[k] = row[128 + lane];
  }
  const float vc = ltb[(size_t)n * 192 + lane];

  const float4 qv = xytp[(b << 13) + n];
#pragma unroll
  for (int k = 0; k < 16; ++k) {
    float4 g = xytp[(b << 13) + nb[k]];
    float r0 = qv.x - g.x, r1 = qv.y - g.y, r2 = qv.z - g.z, r3 = qv.w - g.w;
    float h = fmaf(r3, w1c[3],
                   fmaf(r2, w1c[2], fmaf(r1, w1c[1], fmaf(r0, w1c[0], b1c))));
    s_h[wave][k][lane] = fmaxf(h, 0.0f);
  }
  __syncthreads();

  float pre[16], apd[16];
#pragma unroll
  for (int k = 0; k < 16; ++k) {
    float acc = b2c;
#pragma unroll
    for (int j4 = 0; j4 < 16; ++j4) {
      float4 h4 = *(const float4*)&s_h[wave][k][j4 * 4];
      acc = fmaf(h4.x, w2c[j4 * 4 + 0], acc);
      acc = fmaf(h4.y, w2c[j4 * 4 + 1], acc);
      acc = fmaf(h4.z, w2c[j4 * 4 + 2], acc);
      acc = fmaf(h4.w, w2c[j4 * 4 + 3], acc);
    }
    pre[k] = (vc - psi[k]) + acc;
    apd[k] = alp[k] + acc;
  }

  float xk[16], m = -INFINITY;
#pragma unroll
  for (int k = 0; k < 16; ++k) {
    float s = pre[k], ss = pre[k] * pre[k];
#pragma unroll
    for (int d = 1; d < 64; d <<= 1) {
      s += __shfl_xor(s, d);
      ss += __shfl_xor(ss, d);
    }
    float mu = s * 0.015625f;
    float var = fmaf(ss, 0.015625f, -mu * mu);
    float inv = 1.0f / sqrtf(var + 1e-5f);
    float lnv = fmaf((pre[k] - mu) * inv, gc, bc);
    xk[k] = lnv * 0.125f;
    m = fmaxf(m, xk[k]);
  }
  float se = 0.f, acc = 0.f;
#pragma unroll
  for (int k = 0; k < 16; ++k) {
    float e = __expf(xk[k] - m);
    se += e;
    acc = fmaf(e, apd[k], acc);
  }
  out[(size_t)pid * 64 + lane] = acc / se;
}

// ---------------------------------------------------------------- launch
extern "C" void kernel_launch(void* const* d_in, const int* in_sizes, int n_in,
                              void* d_out, int out_size, void* d_ws,
                              size_t ws_size, hipStream_t stream) {
  const float4* xytp = (const float4*)d_in[0];
  const float* features = (const float*)d_in[1];
  const float* pe_w1 = (const float*)d_in[2];
  const float* pe_b1 = (const float*)d_in[3];
  const float* pe_w2 = (const float*)d_in[4];
  const float* pe_b2 = (const float*)d_in[5];
  const float* lt_w = (const float*)d_in[6];
  const float* lt_b = (const float*)d_in[7];
  const float* ln_g = (const float*)d_in[8];
  const float* ln_b = (const float*)d_in[9];
  float* out = (float*)d_out;

  // ws: idx u16 1MB | aslot 1MB | bslot 1MB | lt 24MB (zbuf = lt[0:32B],
  // written by k_prep, read by k_knn, overwritten later by k_lt)
  char* ws = (char*)d_ws;
  u16* idxbuf = (u16*)ws;                              // 1048576 B
  _Float16* aslot = (_Float16*)(ws + 1048576);         // 1048576 B
  _Float16* bslot = (_Float16*)(ws + 2097152);         // 1048576 B
  float* lt = (float*)(ws + 3145728);                  // 25165824 B
  _Float16* zbuf = (_Float16*)lt;

  k_prep<<<(BATCH * NPTS) / 256, 256, 0, stream>>>(xytp, aslot, bslot, zbuf);
  k_knn<<<BATCH * (NPTS / 16), 256, 0, stream>>>(xytp, aslot, bslot, zbuf,
                                                 idxbuf);
  k_lt<<<(BATCH * NPTS) / 32, 256, 0, stream>>>(features, lt_w, lt_b, lt);
  k_main<<<(BATCH * NPTS) / 4, 256, 0, stream>>>(xytp, lt, idxbuf, pe_w1,
                                                 pe_b1, pe_w2, pe_b2, ln_g,
                                                 ln_b, out);
}